// Round 10
// baseline (727.875 us; speedup 1.0000x reference)
//
#include <hip/hip_runtime.h>
#include <hip/hip_bf16.h>

typedef __attribute__((ext_vector_type(4))) int i32x4;
typedef __attribute__((ext_vector_type(8))) int i32x8;
typedef __attribute__((ext_vector_type(16))) float f32x16;

// exact floor(log2(x)) for x > 0 (handles subnormals)
__device__ __forceinline__ int flog2(float x) {
  unsigned u = __float_as_uint(x);
  int e = (int)((u >> 23) & 255u);
  if (e) return e - 127;
  unsigned m = u & 0x7fffffu;
  return (31 - __clz(m)) - 149;
}

// exact 2^e for e in [-252, 254]
__device__ __forceinline__ float exp2i(int e) {
  int e1 = e >> 1, e2 = e - e1;
  return __uint_as_float((unsigned)(e1 + 127) << 23) *
         __uint_as_float((unsigned)(e2 + 127) << 23);
}

// quantize y (already divided by shared scale) to e2m<MFRAC>, round-half-even, saturate
template <int MFRAC>
__device__ __forceinline__ float qelem(float y, float maxn) {
  float ay = fabsf(y);
  int e = (ay == 0.f) ? 0 : flog2(ay);
  if (e < 0) e = 0;  // min_exp = 0 for ebits=2
  float r = rintf(y * exp2i(MFRAC - e)) * exp2i(e - MFRAC);
  return fminf(fmaxf(r, -maxn), maxn);
}

// general RNE fp32 -> OCP e4m3 encode (|v| <= 448; exact on our folded value grid)
__device__ __forceinline__ unsigned char enc_rne(float v) {
  unsigned u = __float_as_uint(v);
  unsigned s = u >> 31;
  float a = fabsf(v);
  if (a == 0.f) return (unsigned char)(s << 7);
  int e = flog2(a);
  if (e < -6) e = -6;                      // subnormal regime
  int qi = (int)rintf(a * exp2i(3 - e));   // RNE to 3-frac-bit grid -> [0,16]
  if (qi == 0) return (unsigned char)(s << 7);
  if (qi == 16) { qi = 8; e += 1; }
  unsigned exf, m;
  if (qi < 8) { exf = 0u; m = (unsigned)qi; }          // e == -6 subnormal
  else { exf = (unsigned)(e + 7); m = (unsigned)(qi - 8); }
  return (unsigned char)((s << 7) | (exf << 3) | m);
}

__device__ __forceinline__ void gl_lds16(const unsigned char* g, unsigned char* l) {
  __builtin_amdgcn_global_load_lds(
      (const __attribute__((address_space(1))) void*)g,
      (__attribute__((address_space(3))) void*)l, 16, 0, 0);
}

// ------ MX quantization with exponent folding: fp32 -> e4m3 byte = q * 2^(se - se0) ---
template <int MFRAC, int EMAX>
__global__ void quant_fold(const float* __restrict__ in, unsigned char* __restrict__ out,
                           long n4, float maxn, int se0) {
  long i = (long)blockIdx.x * blockDim.x + threadIdx.x;
  long stride = (long)gridDim.x * blockDim.x;
  for (; i < n4; i += stride) {
    float4 v = reinterpret_cast<const float4*>(in)[i];
    float am = fmaxf(fmaxf(fabsf(v.x), fabsf(v.y)), fmaxf(fabsf(v.z), fabsf(v.w)));
    am = fmaxf(am, __shfl_xor(am, 1));
    am = fmaxf(am, __shfl_xor(am, 2));
    am = fmaxf(am, __shfl_xor(am, 4));
    int se = ((am == 0.f) ? 0 : flog2(am)) - EMAX;
    se = se < -127 ? -127 : (se > 127 ? 127 : se);
    float inv = exp2i(-se), f = exp2i(se - se0);
    unsigned o = (unsigned)enc_rne(qelem<MFRAC>(v.x * inv, maxn) * f)
               | ((unsigned)enc_rne(qelem<MFRAC>(v.y * inv, maxn) * f) << 8)
               | ((unsigned)enc_rne(qelem<MFRAC>(v.z * inv, maxn) * f) << 16)
               | ((unsigned)enc_rne(qelem<MFRAC>(v.w * inv, maxn) * f) << 24);
    reinterpret_cast<unsigned*>(out)[i] = o;
  }
}

// fragment read: lane's 32B = [j=0 page 16B | j=1 page (+1024) 16B], K-contiguous
__device__ __forceinline__ i32x8 ld_frag(const unsigned char* p) {
  i32x4 lo = *reinterpret_cast<const i32x4*>(p);
  i32x4 hi = *reinterpret_cast<const i32x4*>(p + 1024);
  i32x8 r;
  r[0] = lo[0]; r[1] = lo[1]; r[2] = lo[2]; r[3] = lo[3];
  r[4] = hi[0]; r[5] = hi[1]; r[6] = hi[2]; r[7] = hi[3];
  return r;
}

// ----- fp8 GEMM, m148 proportions: 128x128 tile, BK=128B, single 32KB LDS buffer, ---
// 4 waves (2x2; wave owns 64x64 = 2x2 accs of 32x32), plain 2-barrier loop.
// All HW scale bytes = 1.0 (0x7f7f7f7f): convention-immune, full MX instruction rate.
// A: [*][lda], B: [*][ldb] e4m3 (folded), lda == ldb required. Product = acc * fac.
// Grid = 32 * nby * KS: bx=n&31, by=(n>>5)%nby, ks=(n>>5)/nby.
// EPI=0: (ks ? Cf2 : Cf)[row*ldC + c0 + col] = acc * fac
// EPI=1: v = silu(gate[row*W + col]) * (acc*fac); fp6-MX quant along 32-col blocks
template <int EPI>
__global__ __launch_bounds__(256) void mx_gemm(
    const unsigned char* __restrict__ A, const unsigned char* __restrict__ B, int lda,
    float* __restrict__ Cf, float* __restrict__ Cf2,
    const float* __restrict__ gate, unsigned char* __restrict__ C8,
    int W, int K, int ldC, int c0, float fac, int se0out, int nby) {
  __shared__ __align__(16) unsigned char sA[16384], sB[16384];
  const int t = threadIdx.x, l = t & 63, w = t >> 6;
  const int wr = w >> 1, wc = w & 1;          // 2x2 wave grid; wave tile 64x64
  const int lr = l & 31, lg = l >> 5;
  const int n = (int)blockIdx.x;
  const int bx = n & 31, by = (n >> 5) % nby, ks = (n >> 5) / nby;
  const int rowA = bx * 128, rowB = by * 128;
  const int k0 = ks * K, kend = k0 + K;
  const int SCL = 0x7f7f7f7f;  // e8m0 1.0 in every byte: scale path is a no-op

  f32x16 acc[2][2];
#pragma unroll
  for (int i = 0; i < 2; ++i)
#pragma unroll
    for (int j = 0; j < 2; ++j) acc[i][j] = (f32x16)(0.f);

  // staging: 16KB/matrix = 16 chunks of 1KB; thread stages 4 A-chunks + 4 B-chunks.
  // chunk m = w + i*4: sub=m>>2 (32-row subtile), kc=(m>>1)&1 (64B k-chunk), j=m&1.
  // A and B share offsets (lda == ldb).
  int off[4], dst[4];
#pragma unroll
  for (int i = 0; i < 4; ++i) {
    int m = w + i * 4;
    int sub = m >> 2, kc = (m >> 1) & 1, j = m & 1;
    off[i] = (sub * 32 + lr) * lda + kc * 64 + lg * 32 + j * 16;
    dst[i] = sub * 4096 + kc * 2048 + j * 1024 + l * 16;
  }
  const unsigned char* Ab = A + (size_t)rowA * lda;
  const unsigned char* Bb = B + (size_t)rowB * lda;

  // m97/m148 structure: stage -> barrier -> compute (2 k-chunks, 8 MFMA/wave) -> barrier
  for (int kpos = k0; kpos < kend; kpos += 128) {
#pragma unroll
    for (int i = 0; i < 4; ++i) {
      gl_lds16(Ab + off[i] + kpos, sA + dst[i]);
      gl_lds16(Bb + off[i] + kpos, sB + dst[i]);
    }
    __syncthreads();
#pragma unroll
    for (int kc = 0; kc < 2; ++kc) {
      i32x8 af0 = ld_frag(sA + (wr * 2 + 0) * 4096 + kc * 2048 + l * 16);
      i32x8 af1 = ld_frag(sA + (wr * 2 + 1) * 4096 + kc * 2048 + l * 16);
      i32x8 bf0 = ld_frag(sB + (wc * 2 + 0) * 4096 + kc * 2048 + l * 16);
      i32x8 bf1 = ld_frag(sB + (wc * 2 + 1) * 4096 + kc * 2048 + l * 16);
      acc[0][0] = __builtin_amdgcn_mfma_scale_f32_32x32x64_f8f6f4(af0, bf0, acc[0][0], 0, 0, 0, SCL, 0, SCL);
      acc[0][1] = __builtin_amdgcn_mfma_scale_f32_32x32x64_f8f6f4(af0, bf1, acc[0][1], 0, 0, 0, SCL, 0, SCL);
      acc[1][0] = __builtin_amdgcn_mfma_scale_f32_32x32x64_f8f6f4(af1, bf0, acc[1][0], 0, 0, 0, SCL, 0, SCL);
      acc[1][1] = __builtin_amdgcn_mfma_scale_f32_32x32x64_f8f6f4(af1, bf1, acc[1][1], 0, 0, 0, SCL, 0, SCL);
    }
    __syncthreads();
  }

  // 32x32 C/D layout: col = lane&31, row = (reg&3) + 8*(reg>>2) + 4*(lane>>5)
  if (EPI == 0) {
    float* D = ks ? Cf2 : Cf;
#pragma unroll
    for (int m = 0; m < 2; ++m)
#pragma unroll
      for (int nn = 0; nn < 2; ++nn)
#pragma unroll
        for (int r = 0; r < 16; ++r) {
          int row = rowA + wr * 64 + m * 32 + (r & 3) + 8 * (r >> 2) + 4 * lg;
          int col = rowB + wc * 64 + nn * 32 + lr;
          D[(size_t)row * ldC + c0 + col] = acc[m][nn][r] * fac;
        }
  } else {
#pragma unroll
    for (int m = 0; m < 2; ++m)
#pragma unroll
      for (int nn = 0; nn < 2; ++nn)
#pragma unroll
        for (int r = 0; r < 16; ++r) {
          int row = rowA + wr * 64 + m * 32 + (r & 3) + 8 * (r >> 2) + 4 * lg;
          int col = rowB + wc * 64 + nn * 32 + lr;  // chunk-local column in [0, W)
          float u = acc[m][nn][r] * fac;
          float g = gate[(size_t)row * W + col];
          float v = u * (g / (1.f + expf(-g)));
          float am = fabsf(v);
          am = fmaxf(am, __shfl_xor(am, 1));
          am = fmaxf(am, __shfl_xor(am, 2));
          am = fmaxf(am, __shfl_xor(am, 4));
          am = fmaxf(am, __shfl_xor(am, 8));
          am = fmaxf(am, __shfl_xor(am, 16));
          int se = ((am == 0.f) ? 0 : flog2(am)) - 2;
          se = se < -127 ? -127 : (se > 127 ? 127 : se);
          float y = qelem<3>(v * exp2i(-se), 7.5f);
          C8[(size_t)row * ldC + c0 + col] = enc_rne(y * exp2i(se - se0out));
        }
  }
}

__global__ void add_f32(float* __restrict__ out, const float* __restrict__ part, long n4) {
  long i = (long)blockIdx.x * blockDim.x + threadIdx.x;
  long stride = (long)gridDim.x * blockDim.x;
  for (; i < n4; i += stride) {
    float4 a = reinterpret_cast<float4*>(out)[i];
    float4 b = reinterpret_cast<const float4*>(part)[i];
    a.x += b.x; a.y += b.y; a.z += b.z; a.w += b.w;
    reinterpret_cast<float4*>(out)[i] = a;
  }
}

extern "C" void kernel_launch(void* const* d_in, const int* in_sizes, int n_in,
                              void* d_out, int out_size, void* d_ws, size_t ws_size,
                              hipStream_t stream) {
  const float* x = (const float*)d_in[0];
  const float* wg = (const float*)d_in[1];
  const float* wu = (const float*)d_in[2];
  const float* wd = (const float*)d_in[3];
  float* out = (float*)d_out;

  const int S = 4096, H = 2048, I = 8192;

  // per-tensor fold baselines: exact while block se in [se0-6, se0+5]
  const int SE0X = -1, SE0W = -7, SE0I = -2;
  const float FAC_GU = 0.00390625f;     // 2^(SE0X + SE0W) = 2^-8
  const float FAC_DN = 0.001953125f;    // 2^(SE0I + SE0W) = 2^-9

  unsigned char* p = (unsigned char*)d_ws;
  unsigned char* xq8 = p;  p += (size_t)S * H;   //  8.4 MB
  unsigned char* wgq8 = p; p += (size_t)I * H;   // 16.8 MB
  unsigned char* wuq8 = p; p += (size_t)I * H;   // 16.8 MB
  unsigned char* wdq8 = p; p += (size_t)H * I;   // 16.8 MB
  unsigned char* iq8 = p;  p += (size_t)S * I;   // 33.6 MB
  size_t base_bytes = (size_t)(p - (unsigned char*)d_ws);  // ~92 MB
  float* gatef = (float*)p;          // chunked fp32 gate buffer
  float* pf = (float*)p;             // down-GEMM K-split partial (reuses dead gatef)

  // quantize: act fp6 e2m3 (mfrac=3, emax=2, maxn=7.5); weights fp4 e2m1 (1, 2, 6.0)
  quant_fold<3, 2><<<2048, 256, 0, stream>>>(x, xq8, (long)S * H / 4, 7.5f, SE0X);
  quant_fold<1, 2><<<2048, 256, 0, stream>>>(wg, wgq8, (long)I * H / 4, 6.0f, SE0W);
  quant_fold<1, 2><<<2048, 256, 0, stream>>>(wu, wuq8, (long)I * H / 4, 6.0f, SE0W);
  quant_fold<1, 2><<<2048, 256, 0, stream>>>(wd, wdq8, (long)H * I / 4, 6.0f, SE0W);

  // largest power-of-two column chunk W with S*W*4 bytes of fp32 gate fitting
  // (R9 passed with W=8192 -> ws_size >= 220 MB; logic kept for safety)
  size_t avail = ws_size > base_bytes ? ws_size - base_bytes : 0;
  int W = 128;
  for (int cand = I; cand >= 128; cand >>= 1)
    if ((size_t)S * cand * 4 <= avail) { W = cand; break; }

  for (int c0 = 0; c0 < I; c0 += W) {
    int nby = W / 128;
    // gate chunk -> fp32 gatef [S][W]
    mx_gemm<0><<<32 * nby, 256, 0, stream>>>(
        xq8, wgq8 + (size_t)c0 * H, H, gatef, nullptr, nullptr, nullptr,
        W, H, W, 0, FAC_GU, 0, nby);
    // up chunk + SwiGLU + fp6-MX requant (folded) -> iq8 columns [c0, c0+W)
    mx_gemm<1><<<32 * nby, 256, 0, stream>>>(
        xq8, wuq8 + (size_t)c0 * H, H, nullptr, nullptr, gatef, iq8,
        W, H, I, c0, FAC_GU, SE0I, nby);
  }

  // down GEMM, K split in 2 (grid 32*16*2 = 1024): ks=0 -> out, ks=1 -> pf; then add
  mx_gemm<0><<<32 * (H / 128) * 2, 256, 0, stream>>>(
      iq8, wdq8, I, out, pf, nullptr, nullptr,
      H, I / 2, H, 0, FAC_DN, 0, H / 128);
  add_f32<<<2048, 256, 0, stream>>>(out, pf, (long)S * H / 4);
}

// Round 11
// 625.125 us; speedup vs baseline: 1.1644x; 1.1644x over previous
//
#include <hip/hip_runtime.h>
#include <hip/hip_bf16.h>

typedef __attribute__((ext_vector_type(4))) int i32x4;
typedef __attribute__((ext_vector_type(8))) int i32x8;
typedef __attribute__((ext_vector_type(4))) float f32x4;

// exact floor(log2(x)) for x > 0 (handles subnormals)
__device__ __forceinline__ int flog2(float x) {
  unsigned u = __float_as_uint(x);
  int e = (int)((u >> 23) & 255u);
  if (e) return e - 127;
  unsigned m = u & 0x7fffffu;
  return (31 - __clz(m)) - 149;
}

// exact 2^e for e in [-252, 254]
__device__ __forceinline__ float exp2i(int e) {
  int e1 = e >> 1, e2 = e - e1;
  return __uint_as_float((unsigned)(e1 + 127) << 23) *
         __uint_as_float((unsigned)(e2 + 127) << 23);
}

// quantize y (already divided by shared scale) to e2m<MFRAC>, round-half-even, saturate
template <int MFRAC>
__device__ __forceinline__ float qelem(float y, float maxn) {
  float ay = fabsf(y);
  int e = (ay == 0.f) ? 0 : flog2(ay);
  if (e < 0) e = 0;  // min_exp = 0 for ebits=2
  float r = rintf(y * exp2i(MFRAC - e)) * exp2i(e - MFRAC);
  return fminf(fmaxf(r, -maxn), maxn);
}

// general RNE fp32 -> OCP e4m3 encode (|v| <= 448; exact on our folded value grid)
__device__ __forceinline__ unsigned char enc_rne(float v) {
  unsigned u = __float_as_uint(v);
  unsigned s = u >> 31;
  float a = fabsf(v);
  if (a == 0.f) return (unsigned char)(s << 7);
  int e = flog2(a);
  if (e < -6) e = -6;                      // subnormal regime
  int qi = (int)rintf(a * exp2i(3 - e));   // RNE to 3-frac-bit grid -> [0,16]
  if (qi == 0) return (unsigned char)(s << 7);
  if (qi == 16) { qi = 8; e += 1; }
  unsigned exf, m;
  if (qi < 8) { exf = 0u; m = (unsigned)qi; }          // e == -6 subnormal
  else { exf = (unsigned)(e + 7); m = (unsigned)(qi - 8); }
  return (unsigned char)((s << 7) | (exf << 3) | m);
}

__device__ __forceinline__ void gl_lds16(const unsigned char* g, unsigned char* l) {
  __builtin_amdgcn_global_load_lds(
      (const __attribute__((address_space(1))) void*)g,
      (__attribute__((address_space(3))) void*)l, 16, 0, 0);
}

// ------ MX quantization with exponent folding: fp32 -> e4m3 byte = q * 2^(se - se0) ---
template <int MFRAC, int EMAX>
__global__ void quant_fold(const float* __restrict__ in, unsigned char* __restrict__ out,
                           long n4, float maxn, int se0) {
  long i = (long)blockIdx.x * blockDim.x + threadIdx.x;
  long stride = (long)gridDim.x * blockDim.x;
  for (; i < n4; i += stride) {
    float4 v = reinterpret_cast<const float4*>(in)[i];
    float am = fmaxf(fmaxf(fabsf(v.x), fabsf(v.y)), fmaxf(fabsf(v.z), fabsf(v.w)));
    am = fmaxf(am, __shfl_xor(am, 1));
    am = fmaxf(am, __shfl_xor(am, 2));
    am = fmaxf(am, __shfl_xor(am, 4));
    int se = ((am == 0.f) ? 0 : flog2(am)) - EMAX;
    se = se < -127 ? -127 : (se > 127 ? 127 : se);
    float inv = exp2i(-se), f = exp2i(se - se0);
    unsigned o = (unsigned)enc_rne(qelem<MFRAC>(v.x * inv, maxn) * f)
               | ((unsigned)enc_rne(qelem<MFRAC>(v.y * inv, maxn) * f) << 8)
               | ((unsigned)enc_rne(qelem<MFRAC>(v.z * inv, maxn) * f) << 16)
               | ((unsigned)enc_rne(qelem<MFRAC>(v.w * inv, maxn) * f) << 24);
    reinterpret_cast<unsigned*>(out)[i] = o;
  }
}

// fragment read: lane's 32B = [16B page 0 | 16B page (+1024)], K-contiguous per lane.
// b128 at lane*16 is contiguous 1KB per 64-lane wave -> inherently conflict-free.
__device__ __forceinline__ i32x8 ld_frag(const unsigned char* p) {
  i32x4 lo = *reinterpret_cast<const i32x4*>(p);
  i32x4 hi = *reinterpret_cast<const i32x4*>(p + 1024);
  i32x8 r;
  r[0] = lo[0]; r[1] = lo[1]; r[2] = lo[2]; r[3] = lo[3];
  r[4] = hi[0]; r[5] = hi[1]; r[6] = hi[2]; r[7] = hi[3];
  return r;
}

// ----- fp8 GEMM with 16x16x128 MFMA (m148's proven shape): 128x128 tile, BK=128B, ---
// single 32KB LDS, 4 waves (2x2; wave owns 64x64 = 4x4 frags of 16x16), 2-barrier loop.
// All HW scale bytes = 1.0 (0x7f7f7f7f): convention-immune, full MX instruction rate.
// LDS frag page (2KB) = 16 rows x 128 K-bytes; lane l <-> (row l&15, kseg l>>4 of 32B).
// A: [*][lda], B: [*][lda] e4m3 (folded). Product = acc * fac.
// Grid = 32 * nby * KS: bx=n&31, by=(n>>5)%nby, ks=(n>>5)/nby.
// EPI=0: (ks ? Cf2 : Cf)[row*ldC + c0 + col] = acc * fac
// EPI=1: v = silu(gate[row*W + col]) * (acc*fac); fp6-MX quant along 32-col blocks
template <int EPI>
__global__ __launch_bounds__(256) void mx_gemm(
    const unsigned char* __restrict__ A, const unsigned char* __restrict__ B, int lda,
    float* __restrict__ Cf, float* __restrict__ Cf2,
    const float* __restrict__ gate, unsigned char* __restrict__ C8,
    int W, int K, int ldC, int c0, float fac, int se0out, int nby) {
  __shared__ __align__(16) unsigned char sA[16384], sB[16384];
  const int t = threadIdx.x, l = t & 63, w = t >> 6;
  const int wr = w >> 1, wc = w & 1;          // 2x2 wave grid; wave tile 64x64
  const int lr16 = l & 15, lg16 = l >> 4;
  const int n = (int)blockIdx.x;
  const int bx = n & 31, by = (n >> 5) % nby, ks = (n >> 5) / nby;
  const int rowA = bx * 128, rowB = by * 128;
  const int k0 = ks * K, kend = k0 + K;
  const int SCL = 0x7f7f7f7f;  // e8m0 1.0 in every byte: scale path is a no-op

  f32x4 acc[4][4];
#pragma unroll
  for (int i = 0; i < 4; ++i)
#pragma unroll
    for (int j = 0; j < 4; ++j) acc[i][j] = (f32x4)(0.f);

  // staging: 16KB/matrix = 8 frag-pages x 2KB = 16 chunks of 1KB; thread stages
  // 4 A-chunks + 4 B-chunks. chunk m = w + i*4: frag f=m>>1, half j=m&1.
  // src (frag f, lane l, half j) = (f*16 + (l&15))*lda + (l>>4)*32 + j*16.
  int off[4], dst[4];
#pragma unroll
  for (int i = 0; i < 4; ++i) {
    int m = w + i * 4;
    int f = m >> 1, j = m & 1;
    off[i] = (f * 16 + lr16) * lda + lg16 * 32 + j * 16;
    dst[i] = f * 2048 + j * 1024 + l * 16;
  }
  const unsigned char* Ab = A + (size_t)rowA * lda;
  const unsigned char* Bb = B + (size_t)rowB * lda;

  // serial 2-barrier loop (R10 structure; only the MFMA shape differs)
  for (int kpos = k0; kpos < kend; kpos += 128) {
#pragma unroll
    for (int i = 0; i < 4; ++i) {
      gl_lds16(Ab + off[i] + kpos, sA + dst[i]);
      gl_lds16(Bb + off[i] + kpos, sB + dst[i]);
    }
    __syncthreads();
    i32x8 af[4], bf[4];
#pragma unroll
    for (int m = 0; m < 4; ++m) af[m] = ld_frag(sA + (wr * 4 + m) * 2048 + l * 16);
#pragma unroll
    for (int m = 0; m < 4; ++m) bf[m] = ld_frag(sB + (wc * 4 + m) * 2048 + l * 16);
#pragma unroll
    for (int m = 0; m < 4; ++m)
#pragma unroll
      for (int nn = 0; nn < 4; ++nn)
        acc[m][nn] = __builtin_amdgcn_mfma_scale_f32_16x16x128_f8f6f4(
            af[m], bf[nn], acc[m][nn], 0, 0, 0, SCL, 0, SCL);
    __syncthreads();
  }

  // 16x16 C/D layout: col = lane&15, row = (lane>>4)*4 + reg  (m89-verified)
  if (EPI == 0) {
    float* D = ks ? Cf2 : Cf;
#pragma unroll
    for (int m = 0; m < 4; ++m)
#pragma unroll
      for (int nn = 0; nn < 4; ++nn)
#pragma unroll
        for (int r = 0; r < 4; ++r) {
          int row = rowA + wr * 64 + m * 16 + lg16 * 4 + r;
          int col = rowB + wc * 64 + nn * 16 + lr16;
          D[(size_t)row * ldC + c0 + col] = acc[m][nn][r] * fac;
        }
  } else {
#pragma unroll
    for (int m = 0; m < 4; ++m)
#pragma unroll
      for (int p = 0; p < 2; ++p)
#pragma unroll
        for (int r = 0; r < 4; ++r) {
          int row = rowA + wr * 64 + m * 16 + lg16 * 4 + r;
          int col = rowB + wc * 64 + p * 32 + lr16;  // chunk-local column in [0, W)
          float u0 = acc[m][2 * p][r] * fac;
          float u1 = acc[m][2 * p + 1][r] * fac;
          float g0 = gate[(size_t)row * W + col];
          float g1 = gate[(size_t)row * W + col + 16];
          float v0 = u0 * (g0 / (1.f + expf(-g0)));
          float v1 = u1 * (g1 / (1.f + expf(-g1)));
          float am = fmaxf(fabsf(v0), fabsf(v1));
          am = fmaxf(am, __shfl_xor(am, 1));
          am = fmaxf(am, __shfl_xor(am, 2));
          am = fmaxf(am, __shfl_xor(am, 4));
          am = fmaxf(am, __shfl_xor(am, 8));
          int se = ((am == 0.f) ? 0 : flog2(am)) - 2;
          se = se < -127 ? -127 : (se > 127 ? 127 : se);
          float f = exp2i(-se), fo = exp2i(se - se0out);
          C8[(size_t)row * ldC + c0 + col] = enc_rne(qelem<3>(v0 * f, 7.5f) * fo);
          C8[(size_t)row * ldC + c0 + col + 16] = enc_rne(qelem<3>(v1 * f, 7.5f) * fo);
        }
  }
}

__global__ void add_f32(float* __restrict__ out, const float* __restrict__ part, long n4) {
  long i = (long)blockIdx.x * blockDim.x + threadIdx.x;
  long stride = (long)gridDim.x * blockDim.x;
  for (; i < n4; i += stride) {
    float4 a = reinterpret_cast<float4*>(out)[i];
    float4 b = reinterpret_cast<const float4*>(part)[i];
    a.x += b.x; a.y += b.y; a.z += b.z; a.w += b.w;
    reinterpret_cast<float4*>(out)[i] = a;
  }
}

extern "C" void kernel_launch(void* const* d_in, const int* in_sizes, int n_in,
                              void* d_out, int out_size, void* d_ws, size_t ws_size,
                              hipStream_t stream) {
  const float* x = (const float*)d_in[0];
  const float* wg = (const float*)d_in[1];
  const float* wu = (const float*)d_in[2];
  const float* wd = (const float*)d_in[3];
  float* out = (float*)d_out;

  const int S = 4096, H = 2048, I = 8192;

  // per-tensor fold baselines: exact while block se in [se0-6, se0+5]
  const int SE0X = -1, SE0W = -7, SE0I = -2;
  const float FAC_GU = 0.00390625f;     // 2^(SE0X + SE0W) = 2^-8
  const float FAC_DN = 0.001953125f;    // 2^(SE0I + SE0W) = 2^-9

  unsigned char* p = (unsigned char*)d_ws;
  unsigned char* xq8 = p;  p += (size_t)S * H;   //  8.4 MB
  unsigned char* wgq8 = p; p += (size_t)I * H;   // 16.8 MB
  unsigned char* wuq8 = p; p += (size_t)I * H;   // 16.8 MB
  unsigned char* wdq8 = p; p += (size_t)H * I;   // 16.8 MB
  unsigned char* iq8 = p;  p += (size_t)S * I;   // 33.6 MB
  size_t base_bytes = (size_t)(p - (unsigned char*)d_ws);  // ~92 MB
  float* gatef = (float*)p;          // chunked fp32 gate buffer
  float* pf = (float*)p;             // down-GEMM K-split partial (reuses dead gatef)

  // quantize: act fp6 e2m3 (mfrac=3, emax=2, maxn=7.5); weights fp4 e2m1 (1, 2, 6.0)
  quant_fold<3, 2><<<2048, 256, 0, stream>>>(x, xq8, (long)S * H / 4, 7.5f, SE0X);
  quant_fold<1, 2><<<2048, 256, 0, stream>>>(wg, wgq8, (long)I * H / 4, 6.0f, SE0W);
  quant_fold<1, 2><<<2048, 256, 0, stream>>>(wu, wuq8, (long)I * H / 4, 6.0f, SE0W);
  quant_fold<1, 2><<<2048, 256, 0, stream>>>(wd, wdq8, (long)H * I / 4, 6.0f, SE0W);

  // largest power-of-two column chunk W with S*W*4 bytes of fp32 gate fitting
  size_t avail = ws_size > base_bytes ? ws_size - base_bytes : 0;
  int W = 128;
  for (int cand = I; cand >= 128; cand >>= 1)
    if ((size_t)S * cand * 4 <= avail) { W = cand; break; }

  for (int c0 = 0; c0 < I; c0 += W) {
    int nby = W / 128;
    // gate chunk -> fp32 gatef [S][W]
    mx_gemm<0><<<32 * nby, 256, 0, stream>>>(
        xq8, wgq8 + (size_t)c0 * H, H, gatef, nullptr, nullptr, nullptr,
        W, H, W, 0, FAC_GU, 0, nby);
    // up chunk + SwiGLU + fp6-MX requant (folded) -> iq8 columns [c0, c0+W)
    mx_gemm<1><<<32 * nby, 256, 0, stream>>>(
        xq8, wuq8 + (size_t)c0 * H, H, nullptr, nullptr, gatef, iq8,
        W, H, I, c0, FAC_GU, SE0I, nby);
  }

  // down GEMM, K split in 2 (grid 32*16*2 = 1024): ks=0 -> out, ks=1 -> pf; then add
  mx_gemm<0><<<32 * (H / 128) * 2, 256, 0, stream>>>(
      iq8, wdq8, I, out, pf, nullptr, nullptr,
      H, I / 2, H, 0, FAC_DN, 0, H / 128);
  add_f32<<<2048, 256, 0, stream>>>(out, pf, (long)S * H / 4);
}